// Round 2
// baseline (2909.819 us; speedup 1.0000x reference)
//
#include <hip/hip_runtime.h>

// MLA forward. Inputs/outputs fp32 (per reference); internal compute bf16 MFMA.
// B=2 T=2048 C=2048 NH=16 HS=128 NLQ=NLKV=512 DHR=64
//
// Fragment layouts (gfx950, verified per learn_hip m89/m120):
//   A[m][k]: m = lane&15, k = (lane>>4)*8 + j   (8 bf16 / lane)
//   B[k][n]: n = lane&15, k = (lane>>4)*8 + j
//   C/D[row][col]: col = lane&15, row = (lane>>4)*4 + reg

typedef __bf16 bf16;
typedef __bf16 bf16x8 __attribute__((ext_vector_type(8)));
typedef __bf16 bf16x4 __attribute__((ext_vector_type(4)));
typedef float f32x4 __attribute__((ext_vector_type(4)));

#define MFMA16(a, b, c) __builtin_amdgcn_mfma_f32_16x16x32_bf16((a), (b), (c), 0, 0, 0)

// ---------------------------------------------------------------------------
// fp32 -> bf16 batched conversion (9 tensors, descriptor struct by value)
// ---------------------------------------------------------------------------
struct CvtDesc { const float* src; bf16* dst; long long n4; };
struct CvtArgs { CvtDesc d[9]; };

__global__ void convert_many(CvtArgs a)
{
    CvtDesc d = a.d[blockIdx.y];
    long long i = (long long)blockIdx.x * blockDim.x + threadIdx.x;
    long long stride = (long long)gridDim.x * blockDim.x;
    for (; i < d.n4; i += stride) {
        f32x4 v = ((const f32x4*)d.src)[i];
        bf16x4 o;
        o[0] = (bf16)v[0]; o[1] = (bf16)v[1]; o[2] = (bf16)v[2]; o[3] = (bf16)v[3];
        ((bf16x4*)d.dst)[i] = o;
    }
}

// ---------------------------------------------------------------------------
// NT GEMM: C[z][m][n] = sum_k A[m*lda+k] * B[n*ldb+k]   (both K-contiguous)
// Block: 256 thr = 4 waves; tile 64(M) x 64(N); wave w owns rows w*16..w*16+15.
// ---------------------------------------------------------------------------
template <typename OutT>
__global__ __launch_bounds__(256, 2)
void gemm_nt(const bf16* __restrict__ A, const bf16* __restrict__ B,
             OutT* __restrict__ C, int K, int lda, int ldb, int ldc,
             long long sAb, long long sAh, long long sBb, long long sBh,
             long long sCb, long long sCh, int ZH)
{
    int z = blockIdx.z;
    int bb = z / ZH, hh = z % ZH;
    A += bb * sAb + hh * sAh;
    B += bb * sBb + hh * sBh;
    C += bb * sCb + hh * sCh;

    int tid = threadIdx.x;
    int w = tid >> 6, lane = tid & 63, l16 = lane & 15, quad = lane >> 4;
    int m0 = blockIdx.x * 64 + w * 16;
    int n0 = blockIdx.y * 64;

    const bf16* Arow = A + (long long)(m0 + l16) * lda;
    f32x4 acc[4] = {};

    for (int k = 0; k < K; k += 32) {
        bf16x8 a = *(const bf16x8*)(Arow + k + quad * 8);
#pragma unroll
        for (int nt = 0; nt < 4; ++nt) {
            bf16x8 b = *(const bf16x8*)(B + (long long)(n0 + nt * 16 + l16) * ldb + k + quad * 8);
            acc[nt] = MFMA16(a, b, acc[nt]);
        }
    }
#pragma unroll
    for (int nt = 0; nt < 4; ++nt)
#pragma unroll
        for (int r = 0; r < 4; ++r) {
            int row = m0 + quad * 4 + r;
            int col = n0 + nt * 16 + l16;
            C[(long long)row * ldc + col] = (OutT)acc[nt][r];
        }
}

// ---------------------------------------------------------------------------
// NN GEMM: C[z][m][n] = sum_k A[m*lda+k] * B[k*ldb+n]
// B tile (32 x 64) staged transposed into LDS (pad row to 40 for b128 align).
// ---------------------------------------------------------------------------
__global__ __launch_bounds__(256, 2)
void gemm_nn(const bf16* __restrict__ A, const bf16* __restrict__ B,
             bf16* __restrict__ C, int K, int lda, int ldb, int ldc,
             long long sAb, long long sAh, long long sBb, long long sBh,
             long long sCb, long long sCh, int ZH)
{
    __shared__ bf16 BT[64 * 40];  // BT[n_local][k_local], row stride 40

    int z = blockIdx.z;
    int bb = z / ZH, hh = z % ZH;
    A += bb * sAb + hh * sAh;
    B += bb * sBb + hh * sBh;
    C += bb * sCb + hh * sCh;

    int tid = threadIdx.x;
    int w = tid >> 6, lane = tid & 63, l16 = lane & 15, quad = lane >> 4;
    int m0 = blockIdx.x * 64 + w * 16;
    int n0 = blockIdx.y * 64;

    const bf16* Arow = A + (long long)(m0 + l16) * lda;
    f32x4 acc[4] = {};

    int rr = tid >> 3;          // 0..31 (k_local)
    int c0 = (tid & 7) * 8;     // 0..56 (n_local)

    for (int k = 0; k < K; k += 32) {
        __syncthreads();
        {
            bf16x8 v = *(const bf16x8*)(B + (long long)(k + rr) * ldb + n0 + c0);
#pragma unroll
            for (int j = 0; j < 8; ++j) BT[(c0 + j) * 40 + rr] = v[j];
        }
        __syncthreads();

        bf16x8 a = *(const bf16x8*)(Arow + k + quad * 8);
#pragma unroll
        for (int nt = 0; nt < 4; ++nt) {
            bf16x8 b = *(const bf16x8*)(&BT[(nt * 16 + l16) * 40 + quad * 8]);
            acc[nt] = MFMA16(a, b, acc[nt]);
        }
    }
#pragma unroll
    for (int nt = 0; nt < 4; ++nt)
#pragma unroll
        for (int r = 0; r < 4; ++r) {
            int row = m0 + quad * 4 + r;
            int col = n0 + nt * 16 + l16;
            C[(long long)row * ldc + col] = (bf16)acc[nt][r];
        }
}

// ---------------------------------------------------------------------------
// RoPE kernels: write rotated halves into cols 512..575 of Kcat / Qcat.
// cos/sin read directly from fp32 inputs.
// ---------------------------------------------------------------------------
__global__ void rope_k_kernel(const bf16* __restrict__ krr, const float* __restrict__ cosb,
                              const float* __restrict__ sinb, bf16* __restrict__ Kcat)
{
    int i = blockIdx.x * 256 + threadIdx.x;  // B*T*32 = 131072
    int pr = i & 31;
    int row = i >> 5;            // b*2048 + t
    int t = row & 2047;
    float re = (float)krr[row * 64 + 2 * pr];
    float im = (float)krr[row * 64 + 2 * pr + 1];
    float c = cosb[t * 32 + pr];
    float s = sinb[t * 32 + pr];
    long long base = (long long)row * 576 + 512 + 2 * pr;
    Kcat[base]     = (bf16)(re * c - im * s);
    Kcat[base + 1] = (bf16)(re * s + im * c);
}

__global__ void rope_q_kernel(const bf16* __restrict__ qrr, const float* __restrict__ cosb,
                              const float* __restrict__ sinb, bf16* __restrict__ Qcat)
{
    int i = blockIdx.x * 256 + threadIdx.x;  // B*T*NH*32 = 4194304
    int pr = i & 31;
    int h = (i >> 5) & 15;
    int t = (i >> 9) & 2047;
    int b = i >> 20;
    long long src = ((long long)(b * 2048 + t)) * 1024 + h * 64 + 2 * pr;
    float re = (float)qrr[src];
    float im = (float)qrr[src + 1];
    float c = cosb[t * 32 + pr];
    float s = sinb[t * 32 + pr];
    long long dst = ((long long)((b * 16 + h) * 2048 + t)) * 576 + 512 + 2 * pr;
    Qcat[dst]     = (bf16)(re * c - im * s);
    Qcat[dst + 1] = (bf16)(re * s + im * c);
}

// ---------------------------------------------------------------------------
// Causal flash attention (MLA absorbed form).
// Q per (b,h): Qcat[z] (2048 x 576). K per b: Kcat[b] (2048 x 576).
// V = Kcat[:, 0:512]. O -> ctx[z] (2048 x 512), already /l.
// Block: 256 thr (4 waves), 64 Q rows / block, KV tile = 32.
// ---------------------------------------------------------------------------
#define ATTN_SCALE 0.07216878364870322f  // 1/sqrt(192)

__global__ __launch_bounds__(256, 2)
void flash_mla(const bf16* __restrict__ Qcat, const bf16* __restrict__ Kcat,
               bf16* __restrict__ ctx)
{
    __shared__ bf16 VT[512 * 40];     // VT[vcol][s], row stride 40 (16B-aligned reads)
    __shared__ bf16 P[4][16 * 40];    // per-wave P strip, row stride 40

    const int T = 2048;
    int z = blockIdx.y;          // b*16 + h
    int b = z >> 4;
    int qt = blockIdx.x;
    int tid = threadIdx.x;
    int w = tid >> 6, lane = tid & 63, l16 = lane & 15, quad = lane >> 4;

    const bf16* Qb = Qcat + (long long)z * T * 576;
    const bf16* Kb = Kcat + (long long)b * T * 576;
    bf16* Ob = ctx + (long long)z * T * 512;

    int qbase = qt * 64;
    const bf16* Qrow = Qb + (long long)(qbase + w * 16 + l16) * 576;

    f32x4 o[32] = {};
    float mrow[4], lrow[4];
#pragma unroll
    for (int r = 0; r < 4; ++r) { mrow[r] = -1e30f; lrow[r] = 0.f; }

    int ntiles = (qbase + 64) >> 5;
    for (int st = 0; st < ntiles; ++st) {
        int s0 = st << 5;

        __syncthreads();  // protect VT from previous iteration's readers
        // stage V tile (rows s0..s0+31, cols 0..511) transposed into VT
#pragma unroll
        for (int p = 0; p < 8; ++p) {
            int rr = p * 4 + w;
            int c0 = lane * 8;
            bf16x8 v = *(const bf16x8*)(Kb + (long long)(s0 + rr) * 576 + c0);
#pragma unroll
            for (int j = 0; j < 8; ++j) VT[(c0 + j) * 40 + rr] = v[j];
        }
        __syncthreads();

        // S strip: 16 rows x 32 cols (2 n-tiles), K = 576 = 18 steps
        f32x4 sa = {0.f, 0.f, 0.f, 0.f}, sb = {0.f, 0.f, 0.f, 0.f};
        const bf16* K0 = Kb + (long long)(s0 + l16) * 576;
        const bf16* K1 = K0 + 16 * 576;
#pragma unroll
        for (int kk = 0; kk < 18; ++kk) {
            bf16x8 a  = *(const bf16x8*)(Qrow + kk * 32 + quad * 8);
            bf16x8 b0 = *(const bf16x8*)(K0 + kk * 32 + quad * 8);
            bf16x8 b1 = *(const bf16x8*)(K1 + kk * 32 + quad * 8);
            sa = MFMA16(a, b0, sa);
            sb = MFMA16(a, b1, sb);
        }

        // online softmax (rows r = quad*4 + 0..3, cols s0 + {0,16} + l16)
        float alpha[4];
#pragma unroll
        for (int r = 0; r < 4; ++r) {
            int trow = qbase + w * 16 + quad * 4 + r;
            float v0 = sa[r] * ATTN_SCALE;
            float v1 = sb[r] * ATTN_SCALE;
            if (s0 + l16 > trow)      v0 = -1e30f;
            if (s0 + 16 + l16 > trow) v1 = -1e30f;
            float rm = fmaxf(v0, v1);
#pragma unroll
            for (int off = 1; off < 16; off <<= 1)
                rm = fmaxf(rm, __shfl_xor(rm, off, 64));
            float mnew = fmaxf(mrow[r], rm);
            alpha[r] = __expf(mrow[r] - mnew);
            mrow[r] = mnew;
            float p0 = __expf(v0 - mnew);
            float p1 = __expf(v1 - mnew);
            float rs = p0 + p1;
#pragma unroll
            for (int off = 1; off < 16; off <<= 1)
                rs += __shfl_xor(rs, off, 64);
            lrow[r] = lrow[r] * alpha[r] + rs;
            // C-layout -> LDS (A-layout consumed below); intra-wave, LDS in-order
            P[w][(quad * 4 + r) * 40 + l16]      = (bf16)p0;
            P[w][(quad * 4 + r) * 40 + 16 + l16] = (bf16)p1;
        }

        bf16x8 pa = *(const bf16x8*)(&P[w][l16 * 40 + quad * 8]);
#pragma unroll
        for (int nt = 0; nt < 32; ++nt) {
#pragma unroll
            for (int r = 0; r < 4; ++r) o[nt][r] *= alpha[r];
            bf16x8 bv = *(const bf16x8*)(&VT[(nt * 16 + l16) * 40 + quad * 8]);
            o[nt] = MFMA16(pa, bv, o[nt]);
        }
    }

    // epilogue: normalize and store ctx
#pragma unroll
    for (int nt = 0; nt < 32; ++nt)
#pragma unroll
        for (int r = 0; r < 4; ++r) {
            int trow = qbase + w * 16 + quad * 4 + r;
            Ob[(long long)trow * 512 + nt * 16 + l16] = (bf16)(o[nt][r] / lrow[r]);
        }
}

// ---------------------------------------------------------------------------
extern "C" void kernel_launch(void* const* d_in, const int* in_sizes, int n_in,
                              void* d_out, int out_size, void* d_ws, size_t ws_size,
                              hipStream_t stream)
{
    const float* xf    = (const float*)d_in[0];
    const float* cosb  = (const float*)d_in[1];
    const float* sinb  = (const float*)d_in[2];
    const float* Wdqf  = (const float*)d_in[3];
    const float* Wuqf  = (const float*)d_in[4];
    const float* Wdkvf = (const float*)d_in[5];
    const float* Wukf  = (const float*)d_in[6];
    const float* Wuvf  = (const float*)d_in[7];
    const float* Wqrf  = (const float*)d_in[8];
    const float* Wkrf  = (const float*)d_in[9];
    const float* Wof   = (const float*)d_in[10];
    float* y = (float*)d_out;

    // workspace carve-up (bf16 intermediates + bf16 input copies, ~206 MB)
    char* ws = (char*)d_ws;
    bf16* c_q  = (bf16*)ws; ws += (size_t)4096 * 512 * 2;        // 4 MB
    bf16* Kcat = (bf16*)ws; ws += (size_t)4096 * 576 * 2;        // 4.7 MB
    bf16* krr  = (bf16*)ws; ws += (size_t)4096 * 64 * 2;         // 0.5 MB
    bf16* qrr  = (bf16*)ws; ws += (size_t)4096 * 1024 * 2;       // 8 MB
    bf16* vC2  = (bf16*)ws; ws += (size_t)2048 * 512 * 2;        // 2 MB
    bf16* keff = (bf16*)ws; ws += (size_t)16 * 512 * 512 * 2;    // 8 MB
    bf16* Qcat = (bf16*)ws; ws += (size_t)32 * 2048 * 576 * 2;   // 75.5 MB
    bf16* ctx  = (bf16*)ws; ws += (size_t)32 * 2048 * 512 * 2;   // 67 MB
    bf16* x    = (bf16*)ws; ws += (size_t)4096 * 2048 * 2;       // 16.8 MB
    bf16* Wdq  = (bf16*)ws; ws += (size_t)512 * 2048 * 2;        // 2 MB
    bf16* Wuq  = (bf16*)ws; ws += (size_t)2048 * 512 * 2;        // 2 MB
    bf16* Wdkv = (bf16*)ws; ws += (size_t)512 * 2048 * 2;        // 2 MB
    bf16* Wuk  = (bf16*)ws; ws += (size_t)2048 * 512 * 2;        // 2 MB
    bf16* Wuv  = (bf16*)ws; ws += (size_t)2048 * 512 * 2;        // 2 MB
    bf16* Wqr  = (bf16*)ws; ws += (size_t)1024 * 512 * 2;        // 1 MB
    bf16* Wkr  = (bf16*)ws; ws += (size_t)64 * 2048 * 2;         // 0.25 MB
    bf16* Wo   = (bf16*)ws; ws += (size_t)2048 * 2048 * 2;       // 8 MB

    dim3 blk(256);

    // 0. fp32 -> bf16 conversion of all matmul operands
    CvtArgs ca;
    ca.d[0] = {xf,    x,    (long long)4096 * 2048 / 4};
    ca.d[1] = {Wdqf,  Wdq,  (long long)512 * 2048 / 4};
    ca.d[2] = {Wuqf,  Wuq,  (long long)2048 * 512 / 4};
    ca.d[3] = {Wdkvf, Wdkv, (long long)512 * 2048 / 4};
    ca.d[4] = {Wukf,  Wuk,  (long long)2048 * 512 / 4};
    ca.d[5] = {Wuvf,  Wuv,  (long long)2048 * 512 / 4};
    ca.d[6] = {Wqrf,  Wqr,  (long long)1024 * 512 / 4};
    ca.d[7] = {Wkrf,  Wkr,  (long long)64 * 2048 / 4};
    ca.d[8] = {Wof,   Wo,   (long long)2048 * 2048 / 4};
    convert_many<<<dim3(512, 9), blk, 0, stream>>>(ca);

    // 1. c_q = x @ Wdq^T                       (4096 x 512, K=2048)
    gemm_nt<bf16><<<dim3(64, 8, 1), blk, 0, stream>>>(x, Wdq, c_q, 2048, 2048, 2048, 512,
                                                      0, 0, 0, 0, 0, 0, 1);
    // 2. c_kv -> Kcat[:, 0:512]                (4096 x 512, ldc=576)
    gemm_nt<bf16><<<dim3(64, 8, 1), blk, 0, stream>>>(x, Wdkv, Kcat, 2048, 2048, 2048, 576,
                                                      0, 0, 0, 0, 0, 0, 1);
    // 3. k_r_raw = x @ Wkr^T                   (4096 x 64)
    gemm_nt<bf16><<<dim3(64, 1, 1), blk, 0, stream>>>(x, Wkr, krr, 2048, 2048, 2048, 64,
                                                      0, 0, 0, 0, 0, 0, 1);
    // 4. q_r_raw = c_q @ Wqr^T                 (4096 x 1024, K=512)
    gemm_nt<bf16><<<dim3(64, 16, 1), blk, 0, stream>>>(c_q, Wqr, qrr, 512, 512, 512, 1024,
                                                       0, 0, 0, 0, 0, 0, 1);
    // 5. vC2 = Wo @ Wuv                        (2048 x 512, K=2048, NN)
    gemm_nn<<<dim3(32, 8, 1), blk, 0, stream>>>(Wo, Wuv, vC2, 2048, 2048, 512, 512,
                                                0, 0, 0, 0, 0, 0, 1);
    // 6. k_eff[h] = Wuq_r[h] @ Wuk_r[h]        (Z=16, 512 x 512, K=128, NN)
    gemm_nn<<<dim3(8, 8, 16), blk, 0, stream>>>(Wuq, Wuk, keff, 128, 2048, 512, 512,
                                                0, 128, 0, 65536, 0, 262144, 16);
    // 7. q_lat -> Qcat[:, 0:512]               (Z=32, 2048 x 512, K=512, NN)
    gemm_nn<<<dim3(32, 8, 32), blk, 0, stream>>>(c_q, keff, Qcat, 512, 512, 512, 576,
                                                 (long long)2048 * 512, 0,
                                                 0, 262144,
                                                 (long long)16 * 2048 * 576,
                                                 (long long)2048 * 576, 16);
    // 8. RoPE
    rope_k_kernel<<<dim3(512), blk, 0, stream>>>(krr, cosb, sinb, Kcat);
    rope_q_kernel<<<dim3(16384), blk, 0, stream>>>(qrr, cosb, sinb, Qcat);
    // 9. flash attention -> ctx
    flash_mla<<<dim3(32, 32), blk, 0, stream>>>(Qcat, Kcat, ctx);
    // 10. y[b,t,h*128+d] = sum_k ctx[b,h,t,k] * vC2[h*128+d,k]   (Z=32, NT, fp32 out)
    gemm_nt<float><<<dim3(32, 2, 32), blk, 0, stream>>>(ctx, vC2, y, 512, 512, 512, 2048,
                                                        (long long)16 * 2048 * 512,
                                                        (long long)2048 * 512,
                                                        0, 65536,
                                                        (long long)2048 * 2048, 128, 16);
}